// Round 9
// baseline (26246.439 us; speedup 1.0000x reference)
//
#include <hip/hip_runtime.h>

#define NSTATE 16
#define H1 75
#define PF 8          // prefetch depth in triples for the serial kernel

// exact numpy-f32 prior: mul+add (NOT fma) layer 1, sequential-k FMA layer 2.
#define PRIOR_ONE(rxv, jj, dst)                               \
  {                                                           \
    float acc = 0.f;                                          \
    for (int k = 0; k < H1; ++k) {                            \
      float h = __fadd_rn(__fmul_rn((rxv), W1[k]), b1[k]);    \
      h = fmaxf(h, 0.f);                                      \
      acc = __fmaf_rn(h, W2[k * NSTATE + (jj)], acc);         \
    }                                                         \
    (dst) = __fadd_rn(acc, b2[(jj)]);                         \
  }

#define DPP_SWAP(x, CTRL) \
  __int_as_float(__builtin_amdgcn_mov_dpp(__float_as_int(x), (CTRL), 0xF, 0xF, true))

// ---------- K1: priors for all t, grid-wide (255 idle CUs -> busy) ----------
__global__ void priors_kernel(const float* __restrict__ rx,
                              const float* __restrict__ W1,
                              const float* __restrict__ b1,
                              const float* __restrict__ W2,
                              const float* __restrict__ b2,
                              float* __restrict__ q, int T, int qrows) {
  const int id = blockIdx.x * 256 + threadIdx.x;  // id = t*16 + j
  if (id >= qrows * NSTATE) return;
  const int t = id >> 4, j = id & 15;
  float val = 0.f;
  if (t < T) {
    const float rxv = rx[t];
    PRIOR_ONE(rxv, j, val);
  }
  q[id] = val;  // pad rows (t >= T) get deterministic zeros
}

// ---------- K2: the irreducibly-serial ACS, ONE wave, zero barriers --------
// r8-verified 3-phase de Bruijn DPP butterfly; q from global via register
// ring prefetch (off-chain); pre-update u dumped to global hist (off-chain).
__launch_bounds__(64, 1)
__global__ void acs_kernel(const float* __restrict__ q,
                           float* __restrict__ hist, int nblk) {
  const int lane = (int)threadIdx.x & 63;
  // storage index on lane bits (b0,b1,b3); lanes 16..63 replicate.
  const int i3 = (lane & 3) | ((lane >> 1) & 4);
  const int rotr_i = ((i3 >> 1) | (i3 << 2)) & 7;
  const int rotl_i = ((i3 << 1) | (i3 >> 2)) & 7;
  const int s0 = rotr_i, s1 = rotl_i, s2 = i3;       // new state per phase
  const bool r0 = (s0 & 4) != 0, r1 = (s1 & 4) != 0, r2 = (s2 & 4) != 0;
  const int d0 = i3, d1 = rotr_i, d2 = rotl_i;       // pre-update state held
  const bool dumper = (lane < 16) && ((lane & 4) == 0);

  // ring of PF triples of (float2 per phase), statically indexed (full unroll)
  float2 ring[PF][3];
#pragma unroll
  for (int n = 0; n < PF; ++n) {
    const int b = n * 3;
    ring[n][0] = *(const float2*)(q + (b + 0) * NSTATE + 2 * s0);
    ring[n][1] = *(const float2*)(q + (b + 1) * NSTATE + 2 * s1);
    ring[n][2] = *(const float2*)(q + (b + 2) * NSTATE + 2 * s2);
  }

  float w = 0.f;  // S[i] = u[i] at phase 0
  for (int blk = 0; blk < nblk; ++blk) {
#pragma unroll
    for (int nn = 0; nn < PF; ++nn) {
      const int n = blk * PF + nn;
      const int t = n * 3;
      const float2 f0 = ring[nn][0];
      const float2 f1 = ring[nn][1];
      const float2 f2 = ring[nn][2];
      // issue prefetch for triple n+PF (q is padded past the end)
      const int tp = (n + PF) * 3;
      ring[nn][0] = *(const float2*)(q + (tp + 0) * NSTATE + 2 * s0);
      ring[nn][1] = *(const float2*)(q + (tp + 1) * NSTATE + 2 * s1);
      ring[nn][2] = *(const float2*)(q + (tp + 2) * NSTATE + 2 * s2);
      // phase 0: partner = lane^1 (quad_perm [1,0,3,2])
      if (dumper) hist[t * 8 + d0] = w;
      {
        const float wp = DPP_SWAP(w, 0xB1);
        const float we = r0 ? wp : w, wo = r0 ? w : wp;
        w = fminf(__fsub_rn(we, f0.x), __fsub_rn(wo, f0.y));
      }
      // phase 1: partner = lane^2 (quad_perm [2,3,0,1])
      if (dumper) hist[(t + 1) * 8 + d1] = w;
      {
        const float wp = DPP_SWAP(w, 0x4E);
        const float we = r1 ? wp : w, wo = r1 ? w : wp;
        w = fminf(__fsub_rn(we, f1.x), __fsub_rn(wo, f1.y));
      }
      // phase 2: partner = lane^8 (row_ror:8)
      if (dumper) hist[(t + 2) * 8 + d2] = w;
      {
        const float wp = DPP_SWAP(w, 0x128);
        const float we = r2 ? wp : w, wo = r2 ? w : wp;
        w = fminf(__fsub_rn(we, f2.x), __fsub_rn(wo, f2.y));
      }
    }
  }
}

// ---------- K3: bit replay (strict-< first argmin), grid-wide --------------
__global__ void bits_kernel(const float* __restrict__ hist,
                            float* __restrict__ out, int T) {
  const int t = blockIdx.x * 256 + threadIdx.x;
  if (t >= T) return;
  const float4 a = *(const float4*)(hist + t * 8);
  const float4 b = *(const float4*)(hist + t * 8 + 4);
  float m = a.x; int arg = 0;
  if (a.y < m) { m = a.y; arg = 1; }
  if (a.z < m) { m = a.z; arg = 2; }
  if (a.w < m) { m = a.w; arg = 3; }
  if (b.x < m) { m = b.x; arg = 4; }
  if (b.y < m) { m = b.y; arg = 5; }
  if (b.z < m) { m = b.z; arg = 6; }
  if (b.w < m) { m = b.w; arg = 7; }
  out[t] = (float)(arg & 1);
}

// ---------- Fallback: round-8 single-kernel (PASSING, 19.9 ms) --------------
#define CHUNK 252
#define NPROD 960
__launch_bounds__(1024, 1)
__global__ void viterbi_bfly(const float* __restrict__ rx,
                             const float* __restrict__ W1,
                             const float* __restrict__ b1,
                             const float* __restrict__ W2,
                             const float* __restrict__ b2,
                             float* __restrict__ out, int T) {
  __shared__ float q_lds[2][CHUNK][NSTATE];
  __shared__ float hist[2][CHUNK][9];
  const int tid = (int)threadIdx.x;
  const int lane = tid & 63;
  const int j = tid & 15;
  const int nchunks = (T + CHUNK - 1) / CHUNK;
  {
    const int n0 = min(CHUNK, T);
    for (int id = tid; id < n0 * NSTATE; id += 1024) {
      const int tl = id >> 4;
      const float rxv = rx[tl];
      PRIOR_ONE(rxv, j, q_lds[0][tl][j]);
    }
  }
  __syncthreads();
  const int i3 = (lane & 3) | ((lane >> 1) & 4);
  const int rotr_i = ((i3 >> 1) | (i3 << 2)) & 7;
  const int rotl_i = ((i3 << 1) | (i3 >> 2)) & 7;
  const int s0 = rotr_i, s1 = rotl_i, s2 = i3;
  const int q0 = 2 * s0, q1 = 2 * s1, q2 = 2 * s2;
  const bool r0 = (s0 & 4) != 0, r1 = (s1 & 4) != 0, r2 = (s2 & 4) != 0;
  const int d0 = i3, d1 = rotr_i, d2 = rotl_i;
  const bool dumper = (lane < 16) && ((lane & 4) == 0);
  float w = 0.f;
  for (int c = 0; c < nchunks; ++c) {
    const int p = c & 1;
    const int base = c * CHUNK;
    const int nsteps = min(CHUNK, T - base);
    const int npad = ((nsteps + 2) / 3) * 3;
    if (tid < 64) {
      const float* qb = &q_lds[p][0][0];
      float2 f0 = *(const float2*)(qb + 0 * 16 + q0);
      float2 f1 = *(const float2*)(qb + 1 * 16 + q1);
      float2 f2 = *(const float2*)(qb + 2 * 16 + q2);
      for (int tl = 0; tl < npad; tl += 3) {
        const int nt = min(tl + 3, CHUNK - 3);
        float2 g0 = *(const float2*)(qb + (nt + 0) * 16 + q0);
        float2 g1 = *(const float2*)(qb + (nt + 1) * 16 + q1);
        float2 g2 = *(const float2*)(qb + (nt + 2) * 16 + q2);
        if (dumper) hist[p][tl][d0] = w;
        {
          const float wp = DPP_SWAP(w, 0xB1);
          const float we = r0 ? wp : w, wo = r0 ? w : wp;
          w = fminf(__fsub_rn(we, f0.x), __fsub_rn(wo, f0.y));
        }
        if (dumper) hist[p][tl + 1][d1] = w;
        {
          const float wp = DPP_SWAP(w, 0x4E);
          const float we = r1 ? wp : w, wo = r1 ? w : wp;
          w = fminf(__fsub_rn(we, f1.x), __fsub_rn(wo, f1.y));
        }
        if (dumper) hist[p][tl + 2][d2] = w;
        {
          const float wp = DPP_SWAP(w, 0x128);
          const float we = r2 ? wp : w, wo = r2 ? w : wp;
          w = fminf(__fsub_rn(we, f2.x), __fsub_rn(wo, f2.y));
        }
        f0 = g0; f1 = g1; f2 = g2;
      }
    } else {
      const int nc = c + 1;
      if (nc < nchunks) {
        const int nbase = nc * CHUNK;
        const int nn = min(CHUNK, T - nbase);
        for (int id = tid - 64; id < nn * NSTATE; id += NPROD) {
          const int tl = id >> 4;
          const float rxv = rx[nbase + tl];
          PRIOR_ONE(rxv, j, q_lds[1 - p][tl][j]);
        }
      }
      if (c > 0) {
        const int tl = tid - 64;
        if (tl < CHUNK) {
          const float* h = hist[1 - p][tl];
          float m = h[0]; int arg = 0;
          if (h[1] < m) { m = h[1]; arg = 1; }
          if (h[2] < m) { m = h[2]; arg = 2; }
          if (h[3] < m) { m = h[3]; arg = 3; }
          if (h[4] < m) { m = h[4]; arg = 4; }
          if (h[5] < m) { m = h[5]; arg = 5; }
          if (h[6] < m) { m = h[6]; arg = 6; }
          if (h[7] < m) { m = h[7]; arg = 7; }
          out[(c - 1) * CHUNK + tl] = (float)(arg & 1);
        }
      }
    }
    __syncthreads();
  }
  {
    const int c = nchunks - 1;
    const int p = c & 1;
    const int base = c * CHUNK;
    const int nsteps = T - base;
    if (tid < nsteps) {
      const float* h = hist[p][tid];
      float m = h[0]; int arg = 0;
      if (h[1] < m) { m = h[1]; arg = 1; }
      if (h[2] < m) { m = h[2]; arg = 2; }
      if (h[3] < m) { m = h[3]; arg = 3; }
      if (h[4] < m) { m = h[4]; arg = 4; }
      if (h[5] < m) { m = h[5]; arg = 5; }
      if (h[6] < m) { m = h[6]; arg = 6; }
      if (h[7] < m) { m = h[7]; arg = 7; }
      out[base + tid] = (float)(arg & 1);
    }
  }
}

extern "C" void kernel_launch(void* const* d_in, const int* in_sizes, int n_in,
                              void* d_out, int out_size, void* d_ws, size_t ws_size,
                              hipStream_t stream) {
  const float* rx = (const float*)d_in[0];
  const float* W1 = (const float*)d_in[1];
  const float* b1 = (const float*)d_in[2];
  const float* W2 = (const float*)d_in[3];
  const float* b2 = (const float*)d_in[4];
  float* out = (float*)d_out;
  const int T = in_sizes[0];

  const int NT = (T + 2) / 3;                        // triples
  const int NTL = ((NT + PF - 1) / PF) * PF;         // loop-padded triples
  const int qrows = (NTL + PF) * 3;                  // + prefetch overrun pad
  const int hrows = NTL * 3;
  const size_t need = ((size_t)qrows * NSTATE + (size_t)hrows * 8) * 4;

  if (ws_size >= need) {
    float* q = (float*)d_ws;
    float* hist = q + (size_t)qrows * NSTATE;
    const int nblk = NTL / PF;
    priors_kernel<<<(qrows * NSTATE + 255) / 256, 256, 0, stream>>>(
        rx, W1, b1, W2, b2, q, T, qrows);
    acs_kernel<<<1, 64, 0, stream>>>(q, hist, nblk);
    bits_kernel<<<(T + 255) / 256, 256, 0, stream>>>(hist, out, T);
  } else {
    viterbi_bfly<<<1, 1024, 0, stream>>>(rx, W1, b1, W2, b2, out, T);
  }
}

// Round 10
// 11130.013 us; speedup vs baseline: 2.3582x; 2.3582x over previous
//
#include <hip/hip_runtime.h>

#define NSTATE 16
#define H1 75
#define CHUNK 252   // divisible by 3 (butterfly phase period); 84 triples
#define NTRI (CHUNK / 3)

// exact numpy-f32 prior: mul+add (NOT fma) layer 1, sequential-k FMA layer 2.
#define PRIOR_ONE(rxv, jj, dst)                               \
  {                                                           \
    float acc = 0.f;                                          \
    for (int k = 0; k < H1; ++k) {                            \
      float h = __fadd_rn(__fmul_rn((rxv), W1[k]), b1[k]);    \
      h = fmaxf(h, 0.f);                                      \
      acc = __fmaf_rn(h, W2[k * NSTATE + (jj)], acc);         \
    }                                                         \
    (dst) = __fadd_rn(acc, b2[(jj)]);                         \
  }

#define DPP_SWAP(x, CTRL) \
  __int_as_float(__builtin_amdgcn_mov_dpp(__float_as_int(x), (CTRL), 0xF, 0xF, true))

// ---------- K1: priors for all t, grid-wide, stored PAIR-SWIZZLED ----------
// For target state s (pair q[2s],q[2s+1]) with r = bit2(s): store swapped
// when r=1, so the serial chain needs no cndmask. pos(j) = (j&14)|((j^(j>>3))&1).
__global__ void priors_kernel(const float* __restrict__ rx,
                              const float* __restrict__ W1,
                              const float* __restrict__ b1,
                              const float* __restrict__ W2,
                              const float* __restrict__ b2,
                              float* __restrict__ q, int T, int qrows) {
  const int id = blockIdx.x * 256 + threadIdx.x;  // id = t*16 + j
  if (id >= qrows * NSTATE) return;
  const int t = id >> 4, j = id & 15;
  float val = 0.f;
  if (t < T) {
    const float rxv = rx[t];
    PRIOR_ONE(rxv, j, val);
  }
  const int pos = (j & 14) | ((j ^ (j >> 3)) & 1);
  q[(size_t)t * NSTATE + pos] = val;  // pad rows (t >= T): deterministic zeros
}

// ---------- K2: serial ACS + bit replay, 2 waves, LDS-only serial chain ----
// wave 0: r8-verified DPP butterfly on q_lds[p] (depth-4 register ring of
//         ds_read_b64), dumps pre-update u to hist_lds[p].
// wave 1: copies chunk c+1 global->q_lds[1-p]; replays bits for chunk c-1
//         from hist_lds[1-p] (strict-< first argmin, r8 consumer verbatim).
// One barrier per chunk; parity-separated buffers (r4/r8-proven scheme).
__launch_bounds__(128, 1)
__global__ void acs2_kernel(const float* __restrict__ q,
                            float* __restrict__ out, int T, int nchunks) {
  __shared__ float q_lds[2][CHUNK][NSTATE];   // 31.5 KB
  __shared__ float hist_lds[2][CHUNK][9];     // 17.7 KB (pad 9: conflict-free)
  const int tid = (int)threadIdx.x;
  const int lane = tid & 63;

  // ---- prologue: copy chunk 0 into q_lds[0] (all 128 threads) ----
  {
    const float4* src = (const float4*)q;
    float4* dst = (float4*)&q_lds[0][0][0];
    for (int i = tid; i < CHUNK * NSTATE / 4; i += 128) dst[i] = src[i];
  }
  __syncthreads();

  // ---- per-lane butterfly constants (r8-verified) ----
  const int i3 = (lane & 3) | ((lane >> 1) & 4);
  const int rotr_i = ((i3 >> 1) | (i3 << 2)) & 7;
  const int rotl_i = ((i3 << 1) | (i3 >> 2)) & 7;
  const int s0 = rotr_i, s1 = rotl_i, s2 = i3;    // new state per phase
  const int q0 = 2 * s0, q1 = 2 * s1, q2 = 2 * s2;
  const int d0 = i3, d1 = rotr_i, d2 = rotl_i;    // pre-update state held
  const bool dumper = (lane < 16) && ((lane & 4) == 0);

  float w = 0.f;  // S[i] = u[i] at phase 0

  for (int c = 0; c < nchunks; ++c) {
    const int p = c & 1;

    if (tid < 64) {
      // ---- wave 0: serial butterfly, full 252 rows (pad rows deterministic) --
      const float* qb = &q_lds[p][0][0];
      float2 f0[4], f1[4], f2[4];  // ring: 4 triples in flight (~160cy > 120cy ds)
#pragma unroll
      for (int n = 0; n < 4; ++n) {
        f0[n] = *(const float2*)(qb + (3 * n + 0) * NSTATE + q0);
        f1[n] = *(const float2*)(qb + (3 * n + 1) * NSTATE + q1);
        f2[n] = *(const float2*)(qb + (3 * n + 2) * NSTATE + q2);
      }
      for (int it = 0; it < NTRI / 4; ++it) {
#pragma unroll
        for (int n = 0; n < 4; ++n) {
          const int tr = it * 4 + n;
          const int tl = tr * 3;
          const float2 a0 = f0[n], a1 = f1[n], a2 = f2[n];
          const int rb = min(3 * (tr + 4), CHUNK - 3);  // clamped reload base
          f0[n] = *(const float2*)(qb + (rb + 0) * NSTATE + q0);
          f1[n] = *(const float2*)(qb + (rb + 1) * NSTATE + q1);
          f2[n] = *(const float2*)(qb + (rb + 2) * NSTATE + q2);
          if (dumper) hist_lds[p][tl][d0] = w;
          {
            const float wp = DPP_SWAP(w, 0xB1);   // lane^1
            w = fminf(__fsub_rn(w, a0.x), __fsub_rn(wp, a0.y));
          }
          if (dumper) hist_lds[p][tl + 1][d1] = w;
          {
            const float wp = DPP_SWAP(w, 0x4E);   // lane^2
            w = fminf(__fsub_rn(w, a1.x), __fsub_rn(wp, a1.y));
          }
          if (dumper) hist_lds[p][tl + 2][d2] = w;
          {
            const float wp = DPP_SWAP(w, 0x128);  // lane^8 (row_ror:8)
            w = fminf(__fsub_rn(w, a2.x), __fsub_rn(wp, a2.y));
          }
        }
      }
    } else {
      // ---- wave 1: copy chunk c+1 global -> q_lds[1-p] ----
      if (c + 1 < nchunks) {
        const float4* src = (const float4*)(q + (size_t)(c + 1) * CHUNK * NSTATE);
        float4* dst = (float4*)&q_lds[1 - p][0][0];
        for (int i = lane; i < CHUNK * NSTATE / 4; i += 64) dst[i] = src[i];
      }
      // ---- wave 1: bits for chunk c-1 (strict-< first argmin) ----
      if (c > 0) {
        for (int tl = lane; tl < CHUNK; tl += 64) {
          const float* h = hist_lds[1 - p][tl];
          float m = h[0]; int arg = 0;
          if (h[1] < m) { m = h[1]; arg = 1; }
          if (h[2] < m) { m = h[2]; arg = 2; }
          if (h[3] < m) { m = h[3]; arg = 3; }
          if (h[4] < m) { m = h[4]; arg = 4; }
          if (h[5] < m) { m = h[5]; arg = 5; }
          if (h[6] < m) { m = h[6]; arg = 6; }
          if (h[7] < m) { m = h[7]; arg = 7; }
          out[(c - 1) * CHUNK + tl] = (float)(arg & 1);
        }
      }
    }
    __syncthreads();
  }

  // ---- epilogue: bits for the last chunk (all 128 threads) ----
  {
    const int c = nchunks - 1;
    const int p = c & 1;
    const int base = c * CHUNK;
    const int nsteps = T - base;
    for (int tl = tid; tl < nsteps; tl += 128) {
      const float* h = hist_lds[p][tl];
      float m = h[0]; int arg = 0;
      if (h[1] < m) { m = h[1]; arg = 1; }
      if (h[2] < m) { m = h[2]; arg = 2; }
      if (h[3] < m) { m = h[3]; arg = 3; }
      if (h[4] < m) { m = h[4]; arg = 4; }
      if (h[5] < m) { m = h[5]; arg = 5; }
      if (h[6] < m) { m = h[6]; arg = 6; }
      if (h[7] < m) { m = h[7]; arg = 7; }
      out[base + tl] = (float)(arg & 1);
    }
  }
}

// ---------- Fallback: round-8 single-kernel (PASSING, 19.9 ms) --------------
#define NPROD 960
__launch_bounds__(1024, 1)
__global__ void viterbi_bfly(const float* __restrict__ rx,
                             const float* __restrict__ W1,
                             const float* __restrict__ b1,
                             const float* __restrict__ W2,
                             const float* __restrict__ b2,
                             float* __restrict__ out, int T) {
  __shared__ float q_lds[2][CHUNK][NSTATE];
  __shared__ float hist[2][CHUNK][9];
  const int tid = (int)threadIdx.x;
  const int lane = tid & 63;
  const int j = tid & 15;
  const int nchunks = (T + CHUNK - 1) / CHUNK;
  {
    const int n0 = min(CHUNK, T);
    for (int id = tid; id < n0 * NSTATE; id += 1024) {
      const int tl = id >> 4;
      const float rxv = rx[tl];
      PRIOR_ONE(rxv, j, q_lds[0][tl][j]);
    }
  }
  __syncthreads();
  const int i3 = (lane & 3) | ((lane >> 1) & 4);
  const int rotr_i = ((i3 >> 1) | (i3 << 2)) & 7;
  const int rotl_i = ((i3 << 1) | (i3 >> 2)) & 7;
  const int s0 = rotr_i, s1 = rotl_i, s2 = i3;
  const int q0 = 2 * s0, q1 = 2 * s1, q2 = 2 * s2;
  const bool r0 = (s0 & 4) != 0, r1 = (s1 & 4) != 0, r2 = (s2 & 4) != 0;
  const int d0 = i3, d1 = rotr_i, d2 = rotl_i;
  const bool dumper = (lane < 16) && ((lane & 4) == 0);
  float w = 0.f;
  for (int c = 0; c < nchunks; ++c) {
    const int p = c & 1;
    const int base = c * CHUNK;
    const int nsteps = min(CHUNK, T - base);
    const int npad = ((nsteps + 2) / 3) * 3;
    if (tid < 64) {
      const float* qb = &q_lds[p][0][0];
      float2 f0 = *(const float2*)(qb + 0 * 16 + q0);
      float2 f1 = *(const float2*)(qb + 1 * 16 + q1);
      float2 f2 = *(const float2*)(qb + 2 * 16 + q2);
      for (int tl = 0; tl < npad; tl += 3) {
        const int nt = min(tl + 3, CHUNK - 3);
        float2 g0 = *(const float2*)(qb + (nt + 0) * 16 + q0);
        float2 g1 = *(const float2*)(qb + (nt + 1) * 16 + q1);
        float2 g2 = *(const float2*)(qb + (nt + 2) * 16 + q2);
        if (dumper) hist[p][tl][d0] = w;
        {
          const float wp = DPP_SWAP(w, 0xB1);
          const float we = r0 ? wp : w, wo = r0 ? w : wp;
          w = fminf(__fsub_rn(we, f0.x), __fsub_rn(wo, f0.y));
        }
        if (dumper) hist[p][tl + 1][d1] = w;
        {
          const float wp = DPP_SWAP(w, 0x4E);
          const float we = r1 ? wp : w, wo = r1 ? w : wp;
          w = fminf(__fsub_rn(we, f1.x), __fsub_rn(wo, f1.y));
        }
        if (dumper) hist[p][tl + 2][d2] = w;
        {
          const float wp = DPP_SWAP(w, 0x128);
          const float we = r2 ? wp : w, wo = r2 ? w : wp;
          w = fminf(__fsub_rn(we, f2.x), __fsub_rn(wo, f2.y));
        }
        f0 = g0; f1 = g1; f2 = g2;
      }
    } else {
      const int nc = c + 1;
      if (nc < nchunks) {
        const int nbase = nc * CHUNK;
        const int nn = min(CHUNK, T - nbase);
        for (int id = tid - 64; id < nn * NSTATE; id += NPROD) {
          const int tl = id >> 4;
          const float rxv = rx[nbase + tl];
          PRIOR_ONE(rxv, j, q_lds[1 - p][tl][j]);
        }
      }
      if (c > 0) {
        const int tl = tid - 64;
        if (tl < CHUNK) {
          const float* h = hist[1 - p][tl];
          float m = h[0]; int arg = 0;
          if (h[1] < m) { m = h[1]; arg = 1; }
          if (h[2] < m) { m = h[2]; arg = 2; }
          if (h[3] < m) { m = h[3]; arg = 3; }
          if (h[4] < m) { m = h[4]; arg = 4; }
          if (h[5] < m) { m = h[5]; arg = 5; }
          if (h[6] < m) { m = h[6]; arg = 6; }
          if (h[7] < m) { m = h[7]; arg = 7; }
          out[(c - 1) * CHUNK + tl] = (float)(arg & 1);
        }
      }
    }
    __syncthreads();
  }
  {
    const int c = nchunks - 1;
    const int p = c & 1;
    const int base = c * CHUNK;
    const int nsteps = T - base;
    if (tid < nsteps) {
      const float* h = hist[p][tid];
      float m = h[0]; int arg = 0;
      if (h[1] < m) { m = h[1]; arg = 1; }
      if (h[2] < m) { m = h[2]; arg = 2; }
      if (h[3] < m) { m = h[3]; arg = 3; }
      if (h[4] < m) { m = h[4]; arg = 4; }
      if (h[5] < m) { m = h[5]; arg = 5; }
      if (h[6] < m) { m = h[6]; arg = 6; }
      if (h[7] < m) { m = h[7]; arg = 7; }
      out[base + tid] = (float)(arg & 1);
    }
  }
}

extern "C" void kernel_launch(void* const* d_in, const int* in_sizes, int n_in,
                              void* d_out, int out_size, void* d_ws, size_t ws_size,
                              hipStream_t stream) {
  const float* rx = (const float*)d_in[0];
  const float* W1 = (const float*)d_in[1];
  const float* b1 = (const float*)d_in[2];
  const float* W2 = (const float*)d_in[3];
  const float* b2 = (const float*)d_in[4];
  float* out = (float*)d_out;
  const int T = in_sizes[0];

  const int nchunks = (T + CHUNK - 1) / CHUNK;
  const int qrows = nchunks * CHUNK;
  const size_t need = (size_t)qrows * NSTATE * 4;

  if (ws_size >= need) {
    float* q = (float*)d_ws;
    priors_kernel<<<(qrows * NSTATE + 255) / 256, 256, 0, stream>>>(
        rx, W1, b1, W2, b2, q, T, qrows);
    acs2_kernel<<<1, 128, 0, stream>>>(q, out, T, nchunks);
  } else {
    viterbi_bfly<<<1, 1024, 0, stream>>>(rx, W1, b1, W2, b2, out, T);
  }
}

// Round 11
// 10568.214 us; speedup vs baseline: 2.4835x; 1.0532x over previous
//
#include <hip/hip_runtime.h>

#define NSTATE 16
#define H1 75
#define CHUNK 252          // 84 triples per chunk
#define NTRIC (CHUNK / 3)  // 84
#define CFLOATS (NTRIC * 64)  // Q' floats per chunk (84 triples * 8 i3 * 8 slots)

// exact numpy-f32 prior: mul+add (NOT fma) layer 1, sequential-k FMA layer 2.
#define PRIOR_ONE(rxv, jj, dst)                               \
  {                                                           \
    float acc = 0.f;                                          \
    for (int k = 0; k < H1; ++k) {                            \
      float h = __fadd_rn(__fmul_rn((rxv), W1[k]), b1[k]);    \
      h = fmaxf(h, 0.f);                                      \
      acc = __fmaf_rn(h, W2[k * NSTATE + (jj)], acc);         \
    }                                                         \
    (dst) = __fadd_rn(acc, b2[(jj)]);                         \
  }

#define DPP_SWAP(x, CTRL) \
  __int_as_float(__builtin_amdgcn_mov_dpp(__float_as_int(x), (CTRL), 0xF, 0xF, true))

// ---------- K1: priors, grid-wide, stored triple-blocked + pre-swapped -----
// Q'[n][i3][slot]: for serial lane with storage index i3, slots 0-1 = phase-0
// pair, 2-3 = phase-1 pair, 4-5 = phase-2 pair (6,7 pad). Pair pre-swapped by
// r = bit2(state) (r10-proven). Writer (t,j): n=t/3, ph=t%3, s=j>>1, b=j&1.
__global__ void priors_kernel(const float* __restrict__ rx,
                              const float* __restrict__ W1,
                              const float* __restrict__ b1,
                              const float* __restrict__ W2,
                              const float* __restrict__ b2,
                              float* __restrict__ q, int T, int tot) {
  const int id = blockIdx.x * 256 + threadIdx.x;  // id = t*16 + j
  if (id >= tot) return;
  const int t = id >> 4, j = id & 15;
  float val = 0.f;
  if (t < T) {
    const float rxv = rx[t];
    PRIOR_ONE(rxv, j, val);
  }
  const int n = t / 3, ph = t - 3 * n;
  const int s = j >> 1, b = j & 1, r = (s >> 2) & 1;
  const int i3 = (ph == 0) ? (((s << 1) | (s >> 2)) & 7)
               : (ph == 1) ? (((s >> 1) | (s << 2)) & 7) : s;
  const int slot = 2 * ph + (b ^ r);
  q[(size_t)n * 64 + i3 * 8 + slot] = val;
}

// ---------- K2: serial ACS + copy + bits, 3 waves ---------------------------
// wave 0: butterfly only — per triple: 1 ds_read_b128 + 1 ds_read_b64 (imm
//         offsets, invariant base), 3 unpredicated ds_write_b32 (cndmask'd
//         junk address for non-dumper lanes), 12 VALU chain ops.
// wave 1: copy chunk c+1 global -> q_lds[1-p].
// wave 2: bits for chunk c-1 from hist_lds[1-p] (r8 consumer verbatim).
__launch_bounds__(192, 1)
__global__ void acs3_kernel(const float* __restrict__ q,
                            float* __restrict__ out, int T, int nchunks) {
  __shared__ float q_lds[2][CFLOATS];       // 43 KB
  __shared__ float hist_lds[2][CHUNK][9];   // 17.7 KB (pad 9: conflict-free)
  __shared__ float junk[2520];              // 10 KB dead sink for non-dumpers
  const int tid = (int)threadIdx.x;
  const int lane = tid & 63;
  const int wid = tid >> 6;

  // ---- prologue: copy chunk 0 into q_lds[0] (all 192 threads) ----
  {
    const float4* src = (const float4*)q;
    float4* dst = (float4*)&q_lds[0][0];
    for (int i = tid; i < CFLOATS / 4; i += 192) dst[i] = src[i];
  }
  __syncthreads();

  // ---- per-lane butterfly constants (r8/r10-verified) ----
  const int i3 = (lane & 3) | ((lane >> 1) & 4);
  const int rotr_i = ((i3 >> 1) | (i3 << 2)) & 7;
  const int rotl_i = ((i3 << 1) | (i3 >> 2)) & 7;
  const int d0 = i3, d1 = rotr_i, d2 = rotl_i;   // pre-update state held
  const bool dumper = (lane < 16) && ((lane & 4) == 0);

  float w = 0.f;  // S[i] = u[i] at phase 0

  for (int c = 0; c < nchunks; ++c) {
    const int p = c & 1;

    if (wid == 0) {
      // ---- wave 0: serial butterfly over 84 triples ----
      const char* qptr = (const char*)(&q_lds[p][0] + i3 * 8);
      char* const hb = (char*)&hist_lds[p][0][0];
      char* const jb = (char*)junk + lane * 4;
      char* a0 = dumper ? hb + d0 * 4      : jb;
      char* a1 = dumper ? hb + 36 + d1 * 4 : jb + 36;
      char* a2 = dumper ? hb + 72 + d2 * 4 : jb + 72;

      float4 rA[4]; float2 rB[4];  // ring: 4 triples in flight
#pragma unroll
      for (int n = 0; n < 4; ++n) {
        rA[n] = *(const float4*)(qptr + n * 256);
        rB[n] = *(const float2*)(qptr + n * 256 + 16);
      }
      for (int it = 0; it < NTRIC / 4 - 1; ++it) {  // 20 iters: triples 0..79
#pragma unroll
        for (int n = 0; n < 4; ++n) {
          const float4 A = rA[n]; const float2 B = rB[n];
          rA[n] = *(const float4*)(qptr + (n + 4) * 256);
          rB[n] = *(const float2*)(qptr + (n + 4) * 256 + 16);
          *(float*)(a0 + n * 108) = w;
          { const float wp = DPP_SWAP(w, 0xB1);   // lane^1
            w = fminf(__fsub_rn(w, A.x), __fsub_rn(wp, A.y)); }
          *(float*)(a1 + n * 108) = w;
          { const float wp = DPP_SWAP(w, 0x4E);   // lane^2
            w = fminf(__fsub_rn(w, A.z), __fsub_rn(wp, A.w)); }
          *(float*)(a2 + n * 108) = w;
          { const float wp = DPP_SWAP(w, 0x128);  // lane^8 (row_ror:8)
            w = fminf(__fsub_rn(w, B.x), __fsub_rn(wp, B.y)); }
        }
        qptr += 1024; a0 += 432; a1 += 432; a2 += 432;
      }
#pragma unroll
      for (int n = 0; n < 4; ++n) {  // epilogue: triples 80..83, no reload
        const float4 A = rA[n]; const float2 B = rB[n];
        *(float*)(a0 + n * 108) = w;
        { const float wp = DPP_SWAP(w, 0xB1);
          w = fminf(__fsub_rn(w, A.x), __fsub_rn(wp, A.y)); }
        *(float*)(a1 + n * 108) = w;
        { const float wp = DPP_SWAP(w, 0x4E);
          w = fminf(__fsub_rn(w, A.z), __fsub_rn(wp, A.w)); }
        *(float*)(a2 + n * 108) = w;
        { const float wp = DPP_SWAP(w, 0x128);
          w = fminf(__fsub_rn(w, B.x), __fsub_rn(wp, B.y)); }
      }
    } else if (wid == 1) {
      // ---- wave 1: copy chunk c+1 global -> q_lds[1-p] ----
      if (c + 1 < nchunks) {
        const float4* src = (const float4*)(q + (size_t)(c + 1) * CFLOATS);
        float4* dst = (float4*)&q_lds[1 - p][0];
        for (int i = lane; i < CFLOATS / 4; i += 64) dst[i] = src[i];
      }
    } else {
      // ---- wave 2: bits for chunk c-1 (strict-< first argmin) ----
      if (c > 0) {
        for (int tl = lane; tl < CHUNK; tl += 64) {
          const float* h = hist_lds[1 - p][tl];
          float m = h[0]; int arg = 0;
          if (h[1] < m) { m = h[1]; arg = 1; }
          if (h[2] < m) { m = h[2]; arg = 2; }
          if (h[3] < m) { m = h[3]; arg = 3; }
          if (h[4] < m) { m = h[4]; arg = 4; }
          if (h[5] < m) { m = h[5]; arg = 5; }
          if (h[6] < m) { m = h[6]; arg = 6; }
          if (h[7] < m) { m = h[7]; arg = 7; }
          out[(c - 1) * CHUNK + tl] = (float)(arg & 1);
        }
      }
    }
    __syncthreads();
  }

  // ---- epilogue: bits for the last chunk (all 192 threads) ----
  {
    const int c = nchunks - 1;
    const int p = c & 1;
    const int base = c * CHUNK;
    const int nsteps = T - base;
    for (int tl = tid; tl < nsteps; tl += 192) {
      const float* h = hist_lds[p][tl];
      float m = h[0]; int arg = 0;
      if (h[1] < m) { m = h[1]; arg = 1; }
      if (h[2] < m) { m = h[2]; arg = 2; }
      if (h[3] < m) { m = h[3]; arg = 3; }
      if (h[4] < m) { m = h[4]; arg = 4; }
      if (h[5] < m) { m = h[5]; arg = 5; }
      if (h[6] < m) { m = h[6]; arg = 6; }
      if (h[7] < m) { m = h[7]; arg = 7; }
      out[base + tl] = (float)(arg & 1);
    }
  }
}

// ---------- Fallback: round-8 single-kernel (PASSING, 19.9 ms) --------------
#define NPROD 960
__launch_bounds__(1024, 1)
__global__ void viterbi_bfly(const float* __restrict__ rx,
                             const float* __restrict__ W1,
                             const float* __restrict__ b1,
                             const float* __restrict__ W2,
                             const float* __restrict__ b2,
                             float* __restrict__ out, int T) {
  __shared__ float q_lds[2][CHUNK][NSTATE];
  __shared__ float hist[2][CHUNK][9];
  const int tid = (int)threadIdx.x;
  const int lane = tid & 63;
  const int j = tid & 15;
  const int nchunks = (T + CHUNK - 1) / CHUNK;
  {
    const int n0 = min(CHUNK, T);
    for (int id = tid; id < n0 * NSTATE; id += 1024) {
      const int tl = id >> 4;
      const float rxv = rx[tl];
      PRIOR_ONE(rxv, j, q_lds[0][tl][j]);
    }
  }
  __syncthreads();
  const int i3 = (lane & 3) | ((lane >> 1) & 4);
  const int rotr_i = ((i3 >> 1) | (i3 << 2)) & 7;
  const int rotl_i = ((i3 << 1) | (i3 >> 2)) & 7;
  const int s0 = rotr_i, s1 = rotl_i, s2 = i3;
  const int q0 = 2 * s0, q1 = 2 * s1, q2 = 2 * s2;
  const bool r0 = (s0 & 4) != 0, r1 = (s1 & 4) != 0, r2 = (s2 & 4) != 0;
  const int d0 = i3, d1 = rotr_i, d2 = rotl_i;
  const bool dumper = (lane < 16) && ((lane & 4) == 0);
  float w = 0.f;
  for (int c = 0; c < nchunks; ++c) {
    const int p = c & 1;
    const int base = c * CHUNK;
    const int nsteps = min(CHUNK, T - base);
    const int npad = ((nsteps + 2) / 3) * 3;
    if (tid < 64) {
      const float* qb = &q_lds[p][0][0];
      float2 f0 = *(const float2*)(qb + 0 * 16 + q0);
      float2 f1 = *(const float2*)(qb + 1 * 16 + q1);
      float2 f2 = *(const float2*)(qb + 2 * 16 + q2);
      for (int tl = 0; tl < npad; tl += 3) {
        const int nt = min(tl + 3, CHUNK - 3);
        float2 g0 = *(const float2*)(qb + (nt + 0) * 16 + q0);
        float2 g1 = *(const float2*)(qb + (nt + 1) * 16 + q1);
        float2 g2 = *(const float2*)(qb + (nt + 2) * 16 + q2);
        if (dumper) hist[p][tl][d0] = w;
        {
          const float wp = DPP_SWAP(w, 0xB1);
          const float we = r0 ? wp : w, wo = r0 ? w : wp;
          w = fminf(__fsub_rn(we, f0.x), __fsub_rn(wo, f0.y));
        }
        if (dumper) hist[p][tl + 1][d1] = w;
        {
          const float wp = DPP_SWAP(w, 0x4E);
          const float we = r1 ? wp : w, wo = r1 ? w : wp;
          w = fminf(__fsub_rn(we, f1.x), __fsub_rn(wo, f1.y));
        }
        if (dumper) hist[p][tl + 2][d2] = w;
        {
          const float wp = DPP_SWAP(w, 0x128);
          const float we = r2 ? wp : w, wo = r2 ? w : wp;
          w = fminf(__fsub_rn(we, f2.x), __fsub_rn(wo, f2.y));
        }
        f0 = g0; f1 = g1; f2 = g2;
      }
    } else {
      const int nc = c + 1;
      if (nc < nchunks) {
        const int nbase = nc * CHUNK;
        const int nn = min(CHUNK, T - nbase);
        for (int id = tid - 64; id < nn * NSTATE; id += NPROD) {
          const int tl = id >> 4;
          const float rxv = rx[nbase + tl];
          PRIOR_ONE(rxv, j, q_lds[1 - p][tl][j]);
        }
      }
      if (c > 0) {
        const int tl = tid - 64;
        if (tl < CHUNK) {
          const float* h = hist[1 - p][tl];
          float m = h[0]; int arg = 0;
          if (h[1] < m) { m = h[1]; arg = 1; }
          if (h[2] < m) { m = h[2]; arg = 2; }
          if (h[3] < m) { m = h[3]; arg = 3; }
          if (h[4] < m) { m = h[4]; arg = 4; }
          if (h[5] < m) { m = h[5]; arg = 5; }
          if (h[6] < m) { m = h[6]; arg = 6; }
          if (h[7] < m) { m = h[7]; arg = 7; }
          out[(c - 1) * CHUNK + tl] = (float)(arg & 1);
        }
      }
    }
    __syncthreads();
  }
  {
    const int c = nchunks - 1;
    const int p = c & 1;
    const int base = c * CHUNK;
    const int nsteps = T - base;
    if (tid < nsteps) {
      const float* h = hist[p][tid];
      float m = h[0]; int arg = 0;
      if (h[1] < m) { m = h[1]; arg = 1; }
      if (h[2] < m) { m = h[2]; arg = 2; }
      if (h[3] < m) { m = h[3]; arg = 3; }
      if (h[4] < m) { m = h[4]; arg = 4; }
      if (h[5] < m) { m = h[5]; arg = 5; }
      if (h[6] < m) { m = h[6]; arg = 6; }
      if (h[7] < m) { m = h[7]; arg = 7; }
      out[base + tid] = (float)(arg & 1);
    }
  }
}

extern "C" void kernel_launch(void* const* d_in, const int* in_sizes, int n_in,
                              void* d_out, int out_size, void* d_ws, size_t ws_size,
                              hipStream_t stream) {
  const float* rx = (const float*)d_in[0];
  const float* W1 = (const float*)d_in[1];
  const float* b1 = (const float*)d_in[2];
  const float* W2 = (const float*)d_in[3];
  const float* b2 = (const float*)d_in[4];
  float* out = (float*)d_out;
  const int T = in_sizes[0];

  const int nchunks = (T + CHUNK - 1) / CHUNK;
  const int tot = nchunks * CHUNK * NSTATE;          // == nchunks * CFLOATS
  const size_t need = (size_t)tot * 4;

  if (ws_size >= need) {
    float* q = (float*)d_ws;
    priors_kernel<<<(tot + 255) / 256, 256, 0, stream>>>(
        rx, W1, b1, W2, b2, q, T, tot);
    acs3_kernel<<<1, 192, 0, stream>>>(q, out, T, nchunks);
  } else {
    viterbi_bfly<<<1, 1024, 0, stream>>>(rx, W1, b1, W2, b2, out, T);
  }
}

// Round 12
// 8283.060 us; speedup vs baseline: 3.1687x; 1.2759x over previous
//
#include <hip/hip_runtime.h>

#define NSTATE 16
#define H1 75
#define CHUNK 252          // 84 triples per chunk
#define NTRIC (CHUNK / 3)  // 84
#define CFLOATS (NTRIC * 64)  // Q' floats per chunk (84 triples * 8 i3 * 8 slots)

// exact numpy-f32 prior: mul+add (NOT fma) layer 1, sequential-k FMA layer 2.
#define PRIOR_ONE(rxv, jj, dst)                               \
  {                                                           \
    float acc = 0.f;                                          \
    for (int k = 0; k < H1; ++k) {                            \
      float h = __fadd_rn(__fmul_rn((rxv), W1[k]), b1[k]);    \
      h = fmaxf(h, 0.f);                                      \
      acc = __fmaf_rn(h, W2[k * NSTATE + (jj)], acc);         \
    }                                                         \
    (dst) = __fadd_rn(acc, b2[(jj)]);                         \
  }

#define DPP_SWAP(x, CTRL) \
  __int_as_float(__builtin_amdgcn_mov_dpp(__float_as_int(x), (CTRL), 0xF, 0xF, true))

// async global->LDS, 16B per lane, wave-uniform LDS base (HW layout contract)
#define GL2LDS(g, l)                                              \
  __builtin_amdgcn_global_load_lds(                               \
      (const __attribute__((address_space(1))) void*)(g),         \
      (__attribute__((address_space(3))) void*)(l), 16, 0, 0)

// ---------- K1: priors, grid-wide, stored triple-blocked + pre-swapped -----
// Q'[n][i3][slot]: slots 0-1 = phase-0 pair, 2-3 = phase-1, 4-5 = phase-2
// (6,7 pad), pair pre-swapped by r = bit2(state) (r10-proven).
__global__ void priors_kernel(const float* __restrict__ rx,
                              const float* __restrict__ W1,
                              const float* __restrict__ b1,
                              const float* __restrict__ W2,
                              const float* __restrict__ b2,
                              float* __restrict__ q, int T, int tot) {
  const int id = blockIdx.x * 256 + threadIdx.x;  // id = t*16 + j
  if (id >= tot) return;
  const int t = id >> 4, j = id & 15;
  float val = 0.f;
  if (t < T) {
    const float rxv = rx[t];
    PRIOR_ONE(rxv, j, val);
  }
  const int n = t / 3, ph = t - 3 * n;
  const int s = j >> 1, b = j & 1, r = (s >> 2) & 1;
  const int i3 = (ph == 0) ? (((s << 1) | (s >> 2)) & 7)
               : (ph == 1) ? (((s >> 1) | (s << 2)) & 7) : s;
  const int slot = 2 * ph + (b ^ r);
  q[(size_t)n * 64 + i3 * 8 + slot] = val;
}

// ---------- K2: serial ACS + copy + bits, 3 waves ---------------------------
// wave 0: butterfly (byte-identical to r11).
// wave 1: copy chunk c+1 global -> q_lds[1-p] via async global_load_lds
//         (no VGPR round trip, single vmcnt(0) drain) — the r11 copy was the
//         chunk gate (~21 serialized latency rounds).
// wave 2: bits for chunk c-1 from hist_lds[1-p].
__launch_bounds__(192, 1)
__global__ void acs3_kernel(const float* __restrict__ q,
                            float* __restrict__ out, int T, int nchunks) {
  __shared__ float q_lds[2][CFLOATS];       // 43 KB
  __shared__ float hist_lds[2][CHUNK][9];   // 17.7 KB (pad 9: conflict-free)
  __shared__ float junk[2520];              // 10 KB dead sink for non-dumpers
  const int tid = (int)threadIdx.x;
  const int lane = tid & 63;
  const int wid = tid >> 6;

  // ---- prologue: copy chunk 0 into q_lds[0] (all 192 threads) ----
  {
    const float4* src = (const float4*)q;
    float4* dst = (float4*)&q_lds[0][0];
    for (int i = tid; i < CFLOATS / 4; i += 192) dst[i] = src[i];
  }
  __syncthreads();

  // ---- per-lane butterfly constants (r8/r10-verified) ----
  const int i3 = (lane & 3) | ((lane >> 1) & 4);
  const int rotr_i = ((i3 >> 1) | (i3 << 2)) & 7;
  const int rotl_i = ((i3 << 1) | (i3 >> 2)) & 7;
  const int d0 = i3, d1 = rotr_i, d2 = rotl_i;   // pre-update state held
  const bool dumper = (lane < 16) && ((lane & 4) == 0);

  float w = 0.f;  // S[i] = u[i] at phase 0

  for (int c = 0; c < nchunks; ++c) {
    const int p = c & 1;

    if (wid == 0) {
      // ---- wave 0: serial butterfly over 84 triples (r11 body, unchanged) --
      const char* qptr = (const char*)(&q_lds[p][0] + i3 * 8);
      char* const hb = (char*)&hist_lds[p][0][0];
      char* const jb = (char*)junk + lane * 4;
      char* a0 = dumper ? hb + d0 * 4      : jb;
      char* a1 = dumper ? hb + 36 + d1 * 4 : jb + 36;
      char* a2 = dumper ? hb + 72 + d2 * 4 : jb + 72;

      float4 rA[4]; float2 rB[4];  // ring: 4 triples in flight
#pragma unroll
      for (int n = 0; n < 4; ++n) {
        rA[n] = *(const float4*)(qptr + n * 256);
        rB[n] = *(const float2*)(qptr + n * 256 + 16);
      }
      for (int it = 0; it < NTRIC / 4 - 1; ++it) {  // 20 iters: triples 0..79
#pragma unroll
        for (int n = 0; n < 4; ++n) {
          const float4 A = rA[n]; const float2 B = rB[n];
          rA[n] = *(const float4*)(qptr + (n + 4) * 256);
          rB[n] = *(const float2*)(qptr + (n + 4) * 256 + 16);
          *(float*)(a0 + n * 108) = w;
          { const float wp = DPP_SWAP(w, 0xB1);   // lane^1
            w = fminf(__fsub_rn(w, A.x), __fsub_rn(wp, A.y)); }
          *(float*)(a1 + n * 108) = w;
          { const float wp = DPP_SWAP(w, 0x4E);   // lane^2
            w = fminf(__fsub_rn(w, A.z), __fsub_rn(wp, A.w)); }
          *(float*)(a2 + n * 108) = w;
          { const float wp = DPP_SWAP(w, 0x128);  // lane^8 (row_ror:8)
            w = fminf(__fsub_rn(w, B.x), __fsub_rn(wp, B.y)); }
        }
        qptr += 1024; a0 += 432; a1 += 432; a2 += 432;
      }
#pragma unroll
      for (int n = 0; n < 4; ++n) {  // epilogue: triples 80..83, no reload
        const float4 A = rA[n]; const float2 B = rB[n];
        *(float*)(a0 + n * 108) = w;
        { const float wp = DPP_SWAP(w, 0xB1);
          w = fminf(__fsub_rn(w, A.x), __fsub_rn(wp, A.y)); }
        *(float*)(a1 + n * 108) = w;
        { const float wp = DPP_SWAP(w, 0x4E);
          w = fminf(__fsub_rn(w, A.z), __fsub_rn(wp, A.w)); }
        *(float*)(a2 + n * 108) = w;
        { const float wp = DPP_SWAP(w, 0x128);
          w = fminf(__fsub_rn(w, B.x), __fsub_rn(wp, B.y)); }
      }
    } else if (wid == 1) {
      // ---- wave 1: async copy chunk c+1 global -> q_lds[1-p] ----
      if (c + 1 < nchunks) {
        const float* srcbase = q + (size_t)(c + 1) * CFLOATS + lane * 4;
        float* const ldsbase = &q_lds[1 - p][0];
#pragma unroll
        for (int i = 0; i < CFLOATS / 256; ++i) {   // 21 x 1KB, all in flight
          GL2LDS(srcbase + i * 256, ldsbase + i * 256);
        }
        asm volatile("s_waitcnt vmcnt(0)" ::: "memory");
      }
    } else {
      // ---- wave 2: bits for chunk c-1 (strict-< first argmin) ----
      if (c > 0) {
        for (int tl = lane; tl < CHUNK; tl += 64) {
          const float* h = hist_lds[1 - p][tl];
          float m = h[0]; int arg = 0;
          if (h[1] < m) { m = h[1]; arg = 1; }
          if (h[2] < m) { m = h[2]; arg = 2; }
          if (h[3] < m) { m = h[3]; arg = 3; }
          if (h[4] < m) { m = h[4]; arg = 4; }
          if (h[5] < m) { m = h[5]; arg = 5; }
          if (h[6] < m) { m = h[6]; arg = 6; }
          if (h[7] < m) { m = h[7]; arg = 7; }
          out[(c - 1) * CHUNK + tl] = (float)(arg & 1);
        }
      }
    }
    __syncthreads();
  }

  // ---- epilogue: bits for the last chunk (all 192 threads) ----
  {
    const int c = nchunks - 1;
    const int p = c & 1;
    const int base = c * CHUNK;
    const int nsteps = T - base;
    for (int tl = tid; tl < nsteps; tl += 192) {
      const float* h = hist_lds[p][tl];
      float m = h[0]; int arg = 0;
      if (h[1] < m) { m = h[1]; arg = 1; }
      if (h[2] < m) { m = h[2]; arg = 2; }
      if (h[3] < m) { m = h[3]; arg = 3; }
      if (h[4] < m) { m = h[4]; arg = 4; }
      if (h[5] < m) { m = h[5]; arg = 5; }
      if (h[6] < m) { m = h[6]; arg = 6; }
      if (h[7] < m) { m = h[7]; arg = 7; }
      out[base + tl] = (float)(arg & 1);
    }
  }
}

// ---------- Fallback: round-8 single-kernel (PASSING, 19.9 ms) --------------
#define NPROD 960
__launch_bounds__(1024, 1)
__global__ void viterbi_bfly(const float* __restrict__ rx,
                             const float* __restrict__ W1,
                             const float* __restrict__ b1,
                             const float* __restrict__ W2,
                             const float* __restrict__ b2,
                             float* __restrict__ out, int T) {
  __shared__ float q_lds[2][CHUNK][NSTATE];
  __shared__ float hist[2][CHUNK][9];
  const int tid = (int)threadIdx.x;
  const int lane = tid & 63;
  const int j = tid & 15;
  const int nchunks = (T + CHUNK - 1) / CHUNK;
  {
    const int n0 = min(CHUNK, T);
    for (int id = tid; id < n0 * NSTATE; id += 1024) {
      const int tl = id >> 4;
      const float rxv = rx[tl];
      PRIOR_ONE(rxv, j, q_lds[0][tl][j]);
    }
  }
  __syncthreads();
  const int i3 = (lane & 3) | ((lane >> 1) & 4);
  const int rotr_i = ((i3 >> 1) | (i3 << 2)) & 7;
  const int rotl_i = ((i3 << 1) | (i3 >> 2)) & 7;
  const int s0 = rotr_i, s1 = rotl_i, s2 = i3;
  const int q0 = 2 * s0, q1 = 2 * s1, q2 = 2 * s2;
  const bool r0 = (s0 & 4) != 0, r1 = (s1 & 4) != 0, r2 = (s2 & 4) != 0;
  const int d0 = i3, d1 = rotr_i, d2 = rotl_i;
  const bool dumper = (lane < 16) && ((lane & 4) == 0);
  float w = 0.f;
  for (int c = 0; c < nchunks; ++c) {
    const int p = c & 1;
    const int base = c * CHUNK;
    const int nsteps = min(CHUNK, T - base);
    const int npad = ((nsteps + 2) / 3) * 3;
    if (tid < 64) {
      const float* qb = &q_lds[p][0][0];
      float2 f0 = *(const float2*)(qb + 0 * 16 + q0);
      float2 f1 = *(const float2*)(qb + 1 * 16 + q1);
      float2 f2 = *(const float2*)(qb + 2 * 16 + q2);
      for (int tl = 0; tl < npad; tl += 3) {
        const int nt = min(tl + 3, CHUNK - 3);
        float2 g0 = *(const float2*)(qb + (nt + 0) * 16 + q0);
        float2 g1 = *(const float2*)(qb + (nt + 1) * 16 + q1);
        float2 g2 = *(const float2*)(qb + (nt + 2) * 16 + q2);
        if (dumper) hist[p][tl][d0] = w;
        {
          const float wp = DPP_SWAP(w, 0xB1);
          const float we = r0 ? wp : w, wo = r0 ? w : wp;
          w = fminf(__fsub_rn(we, f0.x), __fsub_rn(wo, f0.y));
        }
        if (dumper) hist[p][tl + 1][d1] = w;
        {
          const float wp = DPP_SWAP(w, 0x4E);
          const float we = r1 ? wp : w, wo = r1 ? w : wp;
          w = fminf(__fsub_rn(we, f1.x), __fsub_rn(wo, f1.y));
        }
        if (dumper) hist[p][tl + 2][d2] = w;
        {
          const float wp = DPP_SWAP(w, 0x128);
          const float we = r2 ? wp : w, wo = r2 ? w : wp;
          w = fminf(__fsub_rn(we, f2.x), __fsub_rn(wo, f2.y));
        }
        f0 = g0; f1 = g1; f2 = g2;
      }
    } else {
      const int nc = c + 1;
      if (nc < nchunks) {
        const int nbase = nc * CHUNK;
        const int nn = min(CHUNK, T - nbase);
        for (int id = tid - 64; id < nn * NSTATE; id += NPROD) {
          const int tl = id >> 4;
          const float rxv = rx[nbase + tl];
          PRIOR_ONE(rxv, j, q_lds[1 - p][tl][j]);
        }
      }
      if (c > 0) {
        const int tl = tid - 64;
        if (tl < CHUNK) {
          const float* h = hist[1 - p][tl];
          float m = h[0]; int arg = 0;
          if (h[1] < m) { m = h[1]; arg = 1; }
          if (h[2] < m) { m = h[2]; arg = 2; }
          if (h[3] < m) { m = h[3]; arg = 3; }
          if (h[4] < m) { m = h[4]; arg = 4; }
          if (h[5] < m) { m = h[5]; arg = 5; }
          if (h[6] < m) { m = h[6]; arg = 6; }
          if (h[7] < m) { m = h[7]; arg = 7; }
          out[(c - 1) * CHUNK + tl] = (float)(arg & 1);
        }
      }
    }
    __syncthreads();
  }
  {
    const int c = nchunks - 1;
    const int p = c & 1;
    const int base = c * CHUNK;
    const int nsteps = T - base;
    if (tid < nsteps) {
      const float* h = hist[p][tid];
      float m = h[0]; int arg = 0;
      if (h[1] < m) { m = h[1]; arg = 1; }
      if (h[2] < m) { m = h[2]; arg = 2; }
      if (h[3] < m) { m = h[3]; arg = 3; }
      if (h[4] < m) { m = h[4]; arg = 4; }
      if (h[5] < m) { m = h[5]; arg = 5; }
      if (h[6] < m) { m = h[6]; arg = 6; }
      if (h[7] < m) { m = h[7]; arg = 7; }
      out[base + tid] = (float)(arg & 1);
    }
  }
}

extern "C" void kernel_launch(void* const* d_in, const int* in_sizes, int n_in,
                              void* d_out, int out_size, void* d_ws, size_t ws_size,
                              hipStream_t stream) {
  const float* rx = (const float*)d_in[0];
  const float* W1 = (const float*)d_in[1];
  const float* b1 = (const float*)d_in[2];
  const float* W2 = (const float*)d_in[3];
  const float* b2 = (const float*)d_in[4];
  float* out = (float*)d_out;
  const int T = in_sizes[0];

  const int nchunks = (T + CHUNK - 1) / CHUNK;
  const int tot = nchunks * CHUNK * NSTATE;          // == nchunks * CFLOATS
  const size_t need = (size_t)tot * 4;

  if (ws_size >= need) {
    float* q = (float*)d_ws;
    priors_kernel<<<(tot + 255) / 256, 256, 0, stream>>>(
        rx, W1, b1, W2, b2, q, T, tot);
    acs3_kernel<<<1, 192, 0, stream>>>(q, out, T, nchunks);
  } else {
    viterbi_bfly<<<1, 1024, 0, stream>>>(rx, W1, b1, W2, b2, out, T);
  }
}